// Round 20
// baseline (413.367 us; speedup 1.0000x reference)
//
#include <hip/hip_runtime.h>
#include <hip/hip_bf16.h>

typedef __attribute__((ext_vector_type(8))) short bf16x8;   // 8 bf16 (4 VGPRs)
typedef __attribute__((ext_vector_type(4))) float f32x4;
typedef __attribute__((ext_vector_type(4))) unsigned short ushort4v;

#define AS1 __attribute__((address_space(1)))
#define AS3 __attribute__((address_space(3)))

__device__ __forceinline__ float bf_bits_to_f(short s) {
  unsigned int u = ((unsigned int)(unsigned short)s) << 16;
  union { unsigned int u; float f; } c; c.u = u; return c.f;
}
// round-to-nearest-even fp32 -> bf16 bits (finite inputs)
__device__ __forceinline__ unsigned short f_to_bf_bits(float f) {
  union { float f; unsigned int u; } c; c.f = f;
  unsigned int r = c.u + 0x7FFFu + ((c.u >> 16) & 1u);
  return (unsigned short)(r >> 16);
}

// LDS chunk swizzle for 64-B rows (r7-measured: 0 bank conflicts with frag reads)
__device__ __forceinline__ int fsw(int row) { return ((row >> 1) & 3) << 4; }

// ---------------- merged prep: cvt Wk -> bf16 | transpose Wv -> WvT bf16 | w = s*Wk bq ----
__global__ __launch_bounds__(256) void prep_kernel(
    const float* __restrict__ Wk, const float* __restrict__ Wv,
    const float* __restrict__ bq,
    unsigned short* __restrict__ wkb, unsigned short* __restrict__ wvt,
    float* __restrict__ w, const float s) {
  const int bi = blockIdx.x;
  if (bi < 256) {
    __shared__ float t[32][33];
    const int tx = threadIdx.x & 31, ty = threadIdx.x >> 5;  // 32 x 8
    const int n0 = (bi & 15) * 32, k0 = (bi >> 4) * 32;
#pragma unroll
    for (int j = 0; j < 4; ++j)
      t[ty + 8 * j][tx] = Wv[(long)(k0 + ty + 8 * j) * 512 + n0 + tx];
    __syncthreads();
#pragma unroll
    for (int j = 0; j < 4; ++j)
      wvt[(long)(n0 + ty + 8 * j) * 512 + k0 + tx] = f_to_bf_bits(t[tx][ty + 8 * j]);
  } else if (bi < 512) {
    const long c = (long)(bi - 256) * 256 + threadIdx.x;
    const f32x4 v = *(const f32x4*)(Wk + c * 4);
    ushort4v o;
    o[0] = f_to_bf_bits(v[0]); o[1] = f_to_bf_bits(v[1]);
    o[2] = f_to_bf_bits(v[2]); o[3] = f_to_bf_bits(v[3]);
    *(ushort4v*)(wkb + c * 4) = o;
  } else {
    const int q = (bi - 512) * 4 + (threadIdx.x >> 6);
    const int lane = threadIdx.x & 63;
    const float* row = Wk + (long)q * 512 + lane * 8;
    const f32x4 a0 = *(const f32x4*)row;
    const f32x4 a1 = *(const f32x4*)(row + 4);
    const f32x4 b0 = *(const f32x4*)(bq + lane * 8);
    const f32x4 b1 = *(const f32x4*)(bq + lane * 8 + 4);
    float d = a0[0]*b0[0] + a0[1]*b0[1] + a0[2]*b0[2] + a0[3]*b0[3]
            + a1[0]*b1[0] + a1[1]*b1[1] + a1[2]*b1[2] + a1[3]*b1[3];
    for (int off = 1; off < 64; off <<= 1) d += __shfl_xor(d, off);
    if (lane == 0) w[q] = d * s;
  }
}

// ---------------- GEMM (128x128 tile, m97 structure + T2 swizzle) ----------------
// Retained for the tiny G = (Wq Wk^T)/sqrt(d) product (AFP32 A path).
template <bool BIAS, bool TRANSOUT, bool AFP32>
__global__ __launch_bounds__(256) void gemm_kernel(
    const void* __restrict__ Aptr,          // [M][K] bf16 bits or fp32, per batch
    const unsigned short* __restrict__ BT,  // [N][K] bf16 bits, per batch
    const float* __restrict__ bias,         // [N] fp32 or null
    unsigned short* __restrict__ Cout,
    const int K, const float scale,
    const long strideA, const long strideBT, const long strideC, const int ldc,
    const int nx, const int ny) {
  __shared__ unsigned short lds[8192];  // A tile [128][32] then B tile [128][32]
  const int nwg = gridDim.x;
  const int chunk = nwg >> 3;
  const int bid = blockIdx.x;
  const int swz = (bid & 7) * chunk + (bid >> 3);
  const int bx = swz % nx;
  const int t1 = swz / nx;
  const int by = t1 % ny;
  const int bz = t1 / ny;

  const int tid = threadIdx.x;
  const int lane = tid & 63;
  const int wv = tid >> 6;          // 0..3
  const int wr = wv >> 1, wc = wv & 1;
  const unsigned short* Ab = (const unsigned short*)Aptr + (long)bz * strideA + (long)by * 128 * K;
  const float* Af = (const float*)Aptr + (long)bz * strideA + (long)by * 128 * K;
  const unsigned short* Bb = BT + (long)bz * strideBT + (long)bx * 128 * K;

  f32x4 acc[4][4];
#pragma unroll
  for (int m = 0; m < 4; ++m)
#pragma unroll
    for (int n = 0; n < 4; ++n) acc[m][n] = (f32x4){0.f, 0.f, 0.f, 0.f};

  const int r15 = lane & 15, g = lane >> 4;
  const int kiters = K >> 5;
  const int asw = fsw(r15);

  int arow[2], acs[2];
#pragma unroll
  for (int i = 0; i < 2; ++i) {
    const int c = i * 4 + wv;
    const int boff = c * 1024 + lane * 16;
    arow[i] = boff >> 6;
    acs[i] = (boff & 63) ^ fsw(arow[i]);
  }
  f32x4 pa[2][2];
  if (AFP32) {
#pragma unroll
    for (int i = 0; i < 2; ++i) {
      const float* s = Af + (long)arow[i] * K + (acs[i] >> 1);
      pa[i][0] = *(const f32x4*)s;
      pa[i][1] = *(const f32x4*)(s + 4);
    }
  }

  for (int kt = 0; kt < kiters; ++kt) {
#pragma unroll
    for (int i = 0; i < 2; ++i) {
      const int c = i * 4 + wv;
      const char* srcB = (const char*)Bb + (long)arow[i] * (K * 2) + kt * 64 + acs[i];
      __builtin_amdgcn_global_load_lds(
          (const AS1 void*)srcB, (AS3 void*)(lds + 4096 + c * 512), 16, 0, 0);
      if (!AFP32) {
        const char* srcA = (const char*)Ab + (long)arow[i] * (K * 2) + kt * 64 + acs[i];
        __builtin_amdgcn_global_load_lds(
            (const AS1 void*)srcA, (AS3 void*)(lds + c * 512), 16, 0, 0);
      }
    }
    if (AFP32) {
#pragma unroll
      for (int i = 0; i < 2; ++i) {
        const int c = i * 4 + wv;
        bf16x8 w;
#pragma unroll
        for (int e = 0; e < 4; ++e) {
          w[e] = (short)f_to_bf_bits(pa[i][0][e]);
          w[4 + e] = (short)f_to_bf_bits(pa[i][1][e]);
        }
        *(bf16x8*)&lds[c * 512 + lane * 8] = w;
      }
      if (kt < kiters - 1) {
#pragma unroll
        for (int i = 0; i < 2; ++i) {
          const float* s = Af + (long)arow[i] * K + (kt + 1) * 32 + (acs[i] >> 1);
          pa[i][0] = *(const f32x4*)s;
          pa[i][1] = *(const f32x4*)(s + 4);
        }
      }
    }
    __syncthreads();

    bf16x8 af[4], bf[4];
#pragma unroll
    for (int m = 0; m < 4; ++m)
      af[m] = *(const bf16x8*)((const char*)lds + (wr * 64 + m * 16 + r15) * 64 + (g * 16 ^ asw));
#pragma unroll
    for (int n = 0; n < 4; ++n)
      bf[n] = *(const bf16x8*)((const char*)lds + 8192 +
                               (wc * 64 + n * 16 + r15) * 64 + (g * 16 ^ asw));
#pragma unroll
    for (int m = 0; m < 4; ++m)
#pragma unroll
      for (int n = 0; n < 4; ++n)
        acc[m][n] = __builtin_amdgcn_mfma_f32_16x16x32_bf16(af[m], bf[n], acc[m][n], 0, 0, 0);
    __syncthreads();
  }

  const long crow0 = (long)by * 128 + wr * 64;
  const long ccol0 = (long)bx * 128 + wc * 64;
#pragma unroll
  for (int n = 0; n < 4; ++n) {
    const long col = ccol0 + n * 16 + r15;
    const float bv = BIAS ? bias[col] : 0.f;
#pragma unroll
    for (int m = 0; m < 4; ++m) {
      const f32x4 v = acc[m][n];
#pragma unroll
      for (int j = 0; j < 4; ++j) {
        const long row = crow0 + m * 16 + g * 4 + j;
        const float val = (v[j] + bv) * scale;
        const long idx = TRANSOUT ? (col * (long)ldc + row) : (row * (long)ldc + col);
        (Cout + (long)bz * strideC)[idx] = f_to_bf_bits(val);
      }
    }
  }
}

// ---------------- combined: V+KM projection | cvt x -> bf16 | cvec ----------------
__global__ __launch_bounds__(256) void projfuse_kernel(
    const float* __restrict__ audio,        // [16][1024][512] fp32
    const unsigned short* __restrict__ wvt, // [512][512] bf16 (Wv^T)
    const unsigned short* __restrict__ G,   // [512][512] bf16
    const float* __restrict__ bv,
    const float* __restrict__ x,            // [16][4096][512] fp32
    const float* __restrict__ w,            // [512]
    unsigned short* __restrict__ Vt,        // [16][512][1024]
    unsigned short* __restrict__ KMb,       // [16][1024][512]
    unsigned short* __restrict__ xb,        // [16][4096][512] bf16
    float* __restrict__ cv) {               // [16*1024]
  __shared__ unsigned short lds[8192];
  const int bid = blockIdx.x;
  const int tid = threadIdx.x;

  if (bid >= 2048) {
    const int lane = tid & 63;
    for (long row = (long)(bid - 2048) * 4 + (tid >> 6); row < 16384; row += 1024) {
      const f32x4 a0 = *(const f32x4*)(audio + row * 512 + lane * 8);
      const f32x4 a1 = *(const f32x4*)(audio + row * 512 + lane * 8 + 4);
      const f32x4 w0 = *(const f32x4*)(w + lane * 8);
      const f32x4 w1 = *(const f32x4*)(w + lane * 8 + 4);
      float d = a0[0]*w0[0] + a0[1]*w0[1] + a0[2]*w0[2] + a0[3]*w0[3]
              + a1[0]*w1[0] + a1[1]*w1[1] + a1[2]*w1[2] + a1[3]*w1[3];
      for (int off = 1; off < 64; off <<= 1) d += __shfl_xor(d, off);
      if (lane == 0) cv[row] = d;
    }
    return;
  }
  if (bid >= 1024) {
    const long nchunks = (long)65536 * 512 / 4;
    for (long c = (long)(bid - 1024) * 256 + tid; c < nchunks; c += 262144) {
      const f32x4 v = *(const f32x4*)(x + c * 4);
      ushort4v o;
      o[0] = f_to_bf_bits(v[0]); o[1] = f_to_bf_bits(v[1]);
      o[2] = f_to_bf_bits(v[2]); o[3] = f_to_bf_bits(v[3]);
      *(ushort4v*)(xb + c * 4) = o;
    }
    return;
  }

  const int swz = (bid & 7) * 128 + (bid >> 3);
  const int bx = swz & 7;
  const int t1 = swz >> 3;
  const int by = t1 & 7;
  const int bz = t1 >> 3;

  const int lane = tid & 63;
  const int wv = tid >> 6;
  const int wr = wv >> 1, wc = wv & 1;
  const float* Af = audio + (long)bz * 1024 * 512 + (long)by * 128 * 512;
  const unsigned short* Bb = (bx < 4) ? (wvt + (long)bx * 128 * 512)
                                      : (G + (long)(bx - 4) * 128 * 512);

  f32x4 acc[4][4];
#pragma unroll
  for (int m = 0; m < 4; ++m)
#pragma unroll
    for (int n = 0; n < 4; ++n) acc[m][n] = (f32x4){0.f, 0.f, 0.f, 0.f};

  const int r15 = lane & 15, g = lane >> 4;
  const int asw = fsw(r15);

  int arow[2], acs[2];
#pragma unroll
  for (int i = 0; i < 2; ++i) {
    const int c = i * 4 + wv;
    const int boff = c * 1024 + lane * 16;
    arow[i] = boff >> 6;
    acs[i] = (boff & 63) ^ fsw(arow[i]);
  }
  f32x4 pa[2][2];
#pragma unroll
  for (int i = 0; i < 2; ++i) {
    const float* sp = Af + (long)arow[i] * 512 + (acs[i] >> 1);
    pa[i][0] = *(const f32x4*)sp;
    pa[i][1] = *(const f32x4*)(sp + 4);
  }

  for (int kt = 0; kt < 16; ++kt) {
#pragma unroll
    for (int i = 0; i < 2; ++i) {
      const int c = i * 4 + wv;
      const char* srcB = (const char*)Bb + (long)arow[i] * 1024 + kt * 64 + acs[i];
      __builtin_amdgcn_global_load_lds(
          (const AS1 void*)srcB, (AS3 void*)(lds + 4096 + c * 512), 16, 0, 0);
    }
#pragma unroll
    for (int i = 0; i < 2; ++i) {
      const int c = i * 4 + wv;
      bf16x8 wq;
#pragma unroll
      for (int e = 0; e < 4; ++e) {
        wq[e] = (short)f_to_bf_bits(pa[i][0][e]);
        wq[4 + e] = (short)f_to_bf_bits(pa[i][1][e]);
      }
      *(bf16x8*)&lds[c * 512 + lane * 8] = wq;
    }
    if (kt < 15) {
#pragma unroll
      for (int i = 0; i < 2; ++i) {
        const float* sp = Af + (long)arow[i] * 512 + (kt + 1) * 32 + (acs[i] >> 1);
        pa[i][0] = *(const f32x4*)sp;
        pa[i][1] = *(const f32x4*)(sp + 4);
      }
    }
    __syncthreads();

    bf16x8 af[4], bf[4];
#pragma unroll
    for (int m = 0; m < 4; ++m)
      af[m] = *(const bf16x8*)((const char*)lds + (wr * 64 + m * 16 + r15) * 64 + (g * 16 ^ asw));
#pragma unroll
    for (int n = 0; n < 4; ++n)
      bf[n] = *(const bf16x8*)((const char*)lds + 8192 +
                               (wc * 64 + n * 16 + r15) * 64 + (g * 16 ^ asw));
#pragma unroll
    for (int m = 0; m < 4; ++m)
#pragma unroll
      for (int n = 0; n < 4; ++n)
        acc[m][n] = __builtin_amdgcn_mfma_f32_16x16x32_bf16(af[m], bf[n], acc[m][n], 0, 0, 0);
    __syncthreads();
  }

  const long crow0 = (long)by * 128 + wr * 64;     // s-index
  const long ccol0 = (long)bx * 128 + wc * 64;     // combined col (0..1023)
#pragma unroll
  for (int n = 0; n < 4; ++n) {
    const long col = ccol0 + n * 16 + r15;
    const float bvv = (bx < 4) ? bv[col] : 0.f;
#pragma unroll
    for (int m = 0; m < 4; ++m) {
      const f32x4 v = acc[m][n];
#pragma unroll
      for (int j = 0; j < 4; ++j) {
        const long row = crow0 + m * 16 + g * 4 + j;
        const float val = v[j] + bvv;
        if (bx < 4)
          Vt[(long)bz * 512 * 1024 + col * 1024 + row] = f_to_bf_bits(val);
        else
          KMb[(long)bz * 1024 * 512 + row * 512 + (col - 512)] = f_to_bf_bits(val);
      }
    }
  }
}

// ---------------- 256x256 GEMM, A-staged ring-4 + B direct global->VGPR ----------------
// DS-writeback-contention experiment: only A goes through global_load_lds (16 KB/slice,
// halved async LDS writes), B frags are read straight from L2-resident global memory at
// phase top (4 x 16 B loads/lane).  LDS = 69 KB -> 2 blocks/CU possible.
// Phase(s): {loadB(s) ; stageA(s+3) ; 8 ds_read A(s) ; vmcnt(2|0) [retires B(s)+A(s+2)] ;
// lgkmcnt(0) [BEFORE barrier: WAR for A-ring overwrite at next phase top] ; s_barrier ;
// prio1 ; 32 MFMA ; prio0}.  A-lead = 1 phase (~1200 cyc > L3/HBM); B covered intra-phase.
// EXPSTATS/DIVSTATS as before.
template <bool EXPSTATS, bool DIVSTATS>
__global__ __launch_bounds__(512, 2) void gemm256_kernel(
    const unsigned short* __restrict__ A,   // [M][K] bf16, per batch
    const unsigned short* __restrict__ BT,  // [N][K] bf16, per batch
    void* __restrict__ Cout,
    const int K,
    const long strideA, const long strideBT, const long strideC, const int ldc,
    const int nx, const int ny, float* __restrict__ stats,
    const float* __restrict__ cbias) {
  __shared__ __align__(16) char aring[4][16384];  // A slices [256][64B]
  __shared__ float ssum[256][4];
  __shared__ float invl[256];

  const int nwg = gridDim.x;
  const int chunk = nwg >> 3;
  const int bid = blockIdx.x;
  const int swz = (bid & 7) * chunk + (bid >> 3);
  const int bx = swz % nx;
  const int t1 = swz / nx;
  const int by = t1 % ny;
  const int bz = t1 / ny;

  const int tid = threadIdx.x;
  const int lane = tid & 63;
  const int w = tid >> 6;            // 0..7
  const int wm = w >> 2, wn = w & 3; // 2 x 4 wave grid
  const int r15 = lane & 15, g = lane >> 4;
  const int asw = fsw(r15);          // A read-side chunk swizzle

  const char* Abyt = (const char*)(A + (long)bz * strideA + (long)by * 256 * K);
  const char* Bbyt = (const char*)(BT + (long)bz * strideBT + (long)bx * 256 * K);
  const long rsb = (long)K * 2;      // bytes per source row

  if (DIVSTATS) {
    if (tid < 256) {
      const f32x4 s = *(const f32x4*)&stats[((long)bz * 4096 + (long)by * 256 + tid) * 4];
      invl[tid] = 1.f / (s[0] + s[1] + s[2] + s[3]);
    }
  }
  __builtin_amdgcn_sched_barrier(0);

  // A staging geometry: thread tid -> physical chunk (tid&3) of row (tid>>2); dest = tid*16.
  const int srow0 = tid >> 2;                           // 0..127
  const int scol = ((tid & 3) << 4) ^ fsw(srow0);       // inverse-swizzled source column
  const long aoff0 = (long)srow0 * rsb + scol;          // rows 0-127
  const long aoff1 = (long)(srow0 + 128) * rsb + scol;  // rows 128-255
  const int dbase = tid * 16;

  auto stageA = [&](int s) {
    char* h = aring[s & 3];
    const long kb = (long)s * 64;
    __builtin_amdgcn_global_load_lds((const AS1 void*)(Abyt + aoff0 + kb),
                                     (AS3 void*)(h + dbase), 16, 0, 0);
    __builtin_amdgcn_global_load_lds((const AS1 void*)(Abyt + aoff1 + kb),
                                     (AS3 void*)(h + 8192 + dbase), 16, 0, 0);
  };

  // B direct-load base: row (wn*64 + n*16 + r15), col-chunk g*16 (linear, no swizzle)
  const char* Bl = Bbyt + (long)(wn * 64 + r15) * rsb + g * 16;
  const long bstep = (long)16 * rsb;   // +16 rows per fragment index

  f32x4 acc[8][4];
#pragma unroll
  for (int m = 0; m < 8; ++m)
#pragma unroll
    for (int n = 0; n < 4; ++n) acc[m][n] = (f32x4){0.f, 0.f, 0.f, 0.f};

  const int kslices = K >> 5;

  // prologue: stage A slices 0,1,2 (6 loads); retire slice 0 (keep 1,2 in flight)
  stageA(0);
  stageA(1);
  stageA(2);
  asm volatile("s_waitcnt vmcnt(4)" ::: "memory");
  __builtin_amdgcn_s_barrier();
  __builtin_amdgcn_sched_barrier(0);

  for (int s = 0; s < kslices; ++s) {
    // B frags for slice s: direct global loads (L2-resident panel)
    bf16x8 fb[4];
#pragma unroll
    for (int n = 0; n < 4; ++n)
      fb[n] = *(const bf16x8*)(Bl + (long)n * bstep + (long)s * 64);
    // stage A slice s+3 into ring slot (s-1)&3 (WAR safe: all waves drained reads(s-1)
    // at phase s-1's lgkmcnt(0)-before-barrier)
    if (s + 3 < kslices) stageA(s + 3);
    // A frags for slice s (resident: retired at phase s-1's vmcnt + barrier)
    const char* hA = aring[s & 3];
    bf16x8 fa[8];
#pragma unroll
    for (int m = 0; m < 8; ++m)
      fa[m] = *(const bf16x8*)(hA + (wm * 128 + m * 16 + r15) * 64 + ((g * 16) ^ asw));
    __builtin_amdgcn_sched_barrier(0);
    // counted wait: retires B(s) (and A(s+1),A(s+2), both >=1 phase old); keeps A(s+3)
    if (s < kslices - 3) asm volatile("s_waitcnt vmcnt(2)" ::: "memory");
    else                 asm volatile("s_waitcnt vmcnt(0)" ::: "memory");
    // own ds_reads drained BEFORE the barrier (WAR prerequisite for next phase's stageA)
    asm volatile("s_waitcnt lgkmcnt(0)" ::: "memory");
    __builtin_amdgcn_s_barrier();
    __builtin_amdgcn_sched_barrier(0);
    __builtin_amdgcn_s_setprio(1);
#pragma unroll
    for (int m = 0; m < 8; ++m)
#pragma unroll
      for (int n = 0; n < 4; ++n)
        acc[m][n] = __builtin_amdgcn_mfma_f32_16x16x32_bf16(fa[m], fb[n], acc[m][n], 0, 0, 0);
    __builtin_amdgcn_s_setprio(0);
    __builtin_amdgcn_sched_barrier(0);
  }

  if (EXPSTATS) {
    // per-column bias (c_j) then exp; per-row softmax terms cancel and were dropped exactly
    float cb[4];
#pragma unroll
    for (int n = 0; n < 4; ++n)
      cb[n] = cbias[(long)bz * 1024 + (long)bx * 256 + wn * 64 + n * 16 + r15];
#pragma unroll
    for (int m = 0; m < 8; ++m)
#pragma unroll
      for (int n = 0; n < 4; ++n)
#pragma unroll
        for (int j = 0; j < 4; ++j) acc[m][n][j] = __expf(acc[m][n][j] + cb[n]);
#pragma unroll
    for (int m = 0; m < 8; ++m)
#pragma unroll
      for (int j = 0; j < 4; ++j) {
        float s = acc[m][0][j] + acc[m][1][j] + acc[m][2][j] + acc[m][3][j];
        s += __shfl_xor(s, 1);
        s += __shfl_xor(s, 2);
        s += __shfl_xor(s, 4);
        s += __shfl_xor(s, 8);
        if (r15 == 0) ssum[wm * 128 + m * 16 + g * 4 + j][wn] = s;
      }
    __syncthreads();
    if (tid < 256) {
      const float t = ssum[tid][0] + ssum[tid][1] + ssum[tid][2] + ssum[tid][3];
      stats[((long)bz * 4096 + (long)by * 256 + tid) * 4 + bx] = t;
    }
  }

  // epilogue: C/D layout col = lane&15, row = (lane>>4)*4 + j
  const long crow0 = (long)by * 256 + wm * 128;
  const long ccol0 = (long)bx * 256 + wn * 64;
#pragma unroll
  for (int m = 0; m < 8; ++m)
#pragma unroll
    for (int j = 0; j < 4; ++j) {
      const int rl = wm * 128 + m * 16 + g * 4 + j;
      const long row = crow0 + m * 16 + g * 4 + j;
#pragma unroll
      for (int n = 0; n < 4; ++n) {
        const long col = ccol0 + n * 16 + r15;
        if (EXPSTATS) {
          ((unsigned short*)Cout + (long)bz * strideC)[row * (long)ldc + col] =
              f_to_bf_bits(acc[m][n][j]);
        } else {
          const float sc = DIVSTATS ? invl[rl] : 1.f;
          ((float*)Cout + (long)bz * strideC)[row * (long)ldc + col] = acc[m][n][j] * sc;
        }
      }
    }
}

extern "C" void kernel_launch(void* const* d_in, const int* in_sizes, int n_in,
                              void* d_out, int out_size, void* d_ws, size_t ws_size,
                              hipStream_t stream) {
  (void)in_sizes; (void)n_in; (void)out_size; (void)ws_size;
  const float* x     = (const float*)d_in[0];  // [16][4096][512]
  const float* audio = (const float*)d_in[1];  // [16][1024][512]
  const float* Wq    = (const float*)d_in[2];  // [512][512]  (in x out)
  const float* bq    = (const float*)d_in[3];
  const float* Wk    = (const float*)d_in[4];
  const float* bk    = (const float*)d_in[5];  (void)bk;  // cancels in softmax
  const float* Wv    = (const float*)d_in[6];
  const float* bv    = (const float*)d_in[7];
  float* out = (float*)d_out;                  // [16][4096][512] fp32

  const float s = 0.044194173824159216f;       // 1/sqrt(512)

  char* ws = (char*)d_ws;
  size_t off = 0;
  auto carve = [&](size_t bytes) { char* p = ws + off; off += (bytes + 255) & ~(size_t)255; return p; };
  unsigned short* xb  = (unsigned short*)carve((size_t)65536 * 512 * 2);  // x bf16
  unsigned short* wkb = (unsigned short*)carve((size_t)512 * 512 * 2);    // Wk bf16 verbatim
  unsigned short* wvt = (unsigned short*)carve((size_t)512 * 512 * 2);    // Wv^T bf16
  unsigned short* G   = (unsigned short*)carve((size_t)512 * 512 * 2);    // G = Wq Wk^T / sqrt(d)
  unsigned short* KMb = (unsigned short*)carve((size_t)16384 * 512 * 2);  // KM = audio G^T
  unsigned short* Vt  = (unsigned short*)carve((size_t)16384 * 512 * 2);  // V^T bf16 [B][512][1024]
  unsigned short* Pb  = (unsigned short*)carve((size_t)65536 * 1024 * 2); // P = exp(S) bf16
  float*          ls  = (float*)carve((size_t)65536 * 4 * 4);             // row sums [B*HW][4]
  float*          wv_ = (float*)carve((size_t)512 * 4);                   // w = s * Wk bq
  float*          cv  = (float*)carve((size_t)16384 * 4);                 // c_j per (b,j)

  // 1) merged prep (Wk cvt + Wv transpose + wvec), then G
  prep_kernel<<<640, 256, 0, stream>>>(Wk, Wv, bq, wkb, wvt, wv_, s);
  gemm_kernel<false, false, true><<<16, 256, 0, stream>>>(
      Wq, wkb, nullptr, G, 512, s, 0, 0, 0, 512, 4, 4);
  // 2) combined: V+KM projections | cvt x->xb | cvec  (one full-GPU dispatch)
  projfuse_kernel<<<2304, 256, 0, stream>>>(audio, wvt, G, bv, x, wv_, Vt, KMb, xb, cv);
  // 3) P = exp(xb KM^T + c_j) bf16 + per-row 256-col partial sums (B-direct core)
  gemm256_kernel<true, false><<<4 * 16 * 16, 512, 0, stream>>>(
      xb, KMb, Pb, 512,
      (long)4096 * 512, (long)1024 * 512, (long)4096 * 1024, 1024, 4, 16, ls, cv);
  // 4) out = (P V) / l
  gemm256_kernel<false, true><<<2 * 16 * 16, 512, 0, stream>>>(
      Pb, Vt, out, 1024,
      (long)4096 * 1024, (long)512 * 1024, (long)4096 * 512, 512, 2, 16, ls, nullptr);
}

// Round 21
// 323.815 us; speedup vs baseline: 1.2766x; 1.2766x over previous
//
#include <hip/hip_runtime.h>
#include <hip/hip_bf16.h>

typedef __attribute__((ext_vector_type(8))) short bf16x8;   // 8 bf16 (4 VGPRs)
typedef __attribute__((ext_vector_type(4))) float f32x4;
typedef __attribute__((ext_vector_type(4))) unsigned short ushort4v;

#define AS1 __attribute__((address_space(1)))
#define AS3 __attribute__((address_space(3)))

__device__ __forceinline__ float bf_bits_to_f(short s) {
  unsigned int u = ((unsigned int)(unsigned short)s) << 16;
  union { unsigned int u; float f; } c; c.u = u; return c.f;
}
// round-to-nearest-even fp32 -> bf16 bits (finite inputs)
__device__ __forceinline__ unsigned short f_to_bf_bits(float f) {
  union { float f; unsigned int u; } c; c.f = f;
  unsigned int r = c.u + 0x7FFFu + ((c.u >> 16) & 1u);
  return (unsigned short)(r >> 16);
}

// LDS chunk swizzle for 64-B rows (r7-measured: 0 bank conflicts with frag reads)
__device__ __forceinline__ int fsw(int row) { return ((row >> 1) & 3) << 4; }

// ---------------- merged prep: cvt Wk -> bf16 | transpose Wv -> WvT bf16 | w = s*Wk bq ----
// blocks 0-255: Wv transpose tile; 256-511: Wk cvt; 512-639: wvec (4 waves each).
__global__ __launch_bounds__(256) void prep_kernel(
    const float* __restrict__ Wk, const float* __restrict__ Wv,
    const float* __restrict__ bq,
    unsigned short* __restrict__ wkb, unsigned short* __restrict__ wvt,
    float* __restrict__ w, const float s) {
  const int bi = blockIdx.x;
  if (bi < 256) {
    __shared__ float t[32][33];
    const int tx = threadIdx.x & 31, ty = threadIdx.x >> 5;  // 32 x 8
    const int n0 = (bi & 15) * 32, k0 = (bi >> 4) * 32;
#pragma unroll
    for (int j = 0; j < 4; ++j)
      t[ty + 8 * j][tx] = Wv[(long)(k0 + ty + 8 * j) * 512 + n0 + tx];
    __syncthreads();
#pragma unroll
    for (int j = 0; j < 4; ++j)
      wvt[(long)(n0 + ty + 8 * j) * 512 + k0 + tx] = f_to_bf_bits(t[tx][ty + 8 * j]);
  } else if (bi < 512) {
    const long c = (long)(bi - 256) * 256 + threadIdx.x;
    const f32x4 v = *(const f32x4*)(Wk + c * 4);
    ushort4v o;
    o[0] = f_to_bf_bits(v[0]); o[1] = f_to_bf_bits(v[1]);
    o[2] = f_to_bf_bits(v[2]); o[3] = f_to_bf_bits(v[3]);
    *(ushort4v*)(wkb + c * 4) = o;
  } else {
    const int q = (bi - 512) * 4 + (threadIdx.x >> 6);
    const int lane = threadIdx.x & 63;
    const float* row = Wk + (long)q * 512 + lane * 8;
    const f32x4 a0 = *(const f32x4*)row;
    const f32x4 a1 = *(const f32x4*)(row + 4);
    const f32x4 b0 = *(const f32x4*)(bq + lane * 8);
    const f32x4 b1 = *(const f32x4*)(bq + lane * 8 + 4);
    float d = a0[0]*b0[0] + a0[1]*b0[1] + a0[2]*b0[2] + a0[3]*b0[3]
            + a1[0]*b1[0] + a1[1]*b1[1] + a1[2]*b1[2] + a1[3]*b1[3];
    for (int off = 1; off < 64; off <<= 1) d += __shfl_xor(d, off);
    if (lane == 0) w[q] = d * s;
  }
}

// ---------------- cv[row] = dot(audio[row][:], w)  (wave per row, fp32 in) ----------------
__global__ __launch_bounds__(256) void cvec_kernel(const float* __restrict__ audio,
                                                   const float* __restrict__ w,
                                                   float* __restrict__ cv) {
  const long row = (long)blockIdx.x * 4 + (threadIdx.x >> 6);  // 16384 rows
  const int lane = threadIdx.x & 63;
  const f32x4 a0 = *(const f32x4*)(audio + row * 512 + lane * 8);
  const f32x4 a1 = *(const f32x4*)(audio + row * 512 + lane * 8 + 4);
  const f32x4 w0 = *(const f32x4*)(w + lane * 8);
  const f32x4 w1 = *(const f32x4*)(w + lane * 8 + 4);
  float d = a0[0]*w0[0] + a0[1]*w0[1] + a0[2]*w0[2] + a0[3]*w0[3]
          + a1[0]*w1[0] + a1[1]*w1[1] + a1[2]*w1[2] + a1[3]*w1[3];
  for (int off = 1; off < 64; off <<= 1) d += __shfl_xor(d, off);
  if (lane == 0) cv[row] = d;
}

// ---------------- GEMM (128x128 tile, m97 structure + T2 swizzle) ----------------
// Retained for the tiny G = (Wq Wk^T)/sqrt(d) product (AFP32 A path).
template <bool BIAS, bool TRANSOUT, bool AFP32>
__global__ __launch_bounds__(256) void gemm_kernel(
    const void* __restrict__ Aptr,          // [M][K] bf16 bits or fp32, per batch
    const unsigned short* __restrict__ BT,  // [N][K] bf16 bits, per batch
    const float* __restrict__ bias,         // [N] fp32 or null
    unsigned short* __restrict__ Cout,
    const int K, const float scale,
    const long strideA, const long strideBT, const long strideC, const int ldc,
    const int nx, const int ny) {
  __shared__ unsigned short lds[8192];  // A tile [128][32] then B tile [128][32]
  const int nwg = gridDim.x;
  const int chunk = nwg >> 3;
  const int bid = blockIdx.x;
  const int swz = (bid & 7) * chunk + (bid >> 3);
  const int bx = swz % nx;
  const int t1 = swz / nx;
  const int by = t1 % ny;
  const int bz = t1 / ny;

  const int tid = threadIdx.x;
  const int lane = tid & 63;
  const int wv = tid >> 6;          // 0..3
  const int wr = wv >> 1, wc = wv & 1;
  const unsigned short* Ab = (const unsigned short*)Aptr + (long)bz * strideA + (long)by * 128 * K;
  const float* Af = (const float*)Aptr + (long)bz * strideA + (long)by * 128 * K;
  const unsigned short* Bb = BT + (long)bz * strideBT + (long)bx * 128 * K;

  f32x4 acc[4][4];
#pragma unroll
  for (int m = 0; m < 4; ++m)
#pragma unroll
    for (int n = 0; n < 4; ++n) acc[m][n] = (f32x4){0.f, 0.f, 0.f, 0.f};

  const int r15 = lane & 15, g = lane >> 4;
  const int kiters = K >> 5;
  const int asw = fsw(r15);

  int arow[2], acs[2];
#pragma unroll
  for (int i = 0; i < 2; ++i) {
    const int c = i * 4 + wv;
    const int boff = c * 1024 + lane * 16;
    arow[i] = boff >> 6;
    acs[i] = (boff & 63) ^ fsw(arow[i]);
  }
  f32x4 pa[2][2];
  if (AFP32) {
#pragma unroll
    for (int i = 0; i < 2; ++i) {
      const float* s = Af + (long)arow[i] * K + (acs[i] >> 1);
      pa[i][0] = *(const f32x4*)s;
      pa[i][1] = *(const f32x4*)(s + 4);
    }
  }

  for (int kt = 0; kt < kiters; ++kt) {
#pragma unroll
    for (int i = 0; i < 2; ++i) {
      const int c = i * 4 + wv;
      const char* srcB = (const char*)Bb + (long)arow[i] * (K * 2) + kt * 64 + acs[i];
      __builtin_amdgcn_global_load_lds(
          (const AS1 void*)srcB, (AS3 void*)(lds + 4096 + c * 512), 16, 0, 0);
      if (!AFP32) {
        const char* srcA = (const char*)Ab + (long)arow[i] * (K * 2) + kt * 64 + acs[i];
        __builtin_amdgcn_global_load_lds(
            (const AS1 void*)srcA, (AS3 void*)(lds + c * 512), 16, 0, 0);
      }
    }
    if (AFP32) {
#pragma unroll
      for (int i = 0; i < 2; ++i) {
        const int c = i * 4 + wv;
        bf16x8 w;
#pragma unroll
        for (int e = 0; e < 4; ++e) {
          w[e] = (short)f_to_bf_bits(pa[i][0][e]);
          w[4 + e] = (short)f_to_bf_bits(pa[i][1][e]);
        }
        *(bf16x8*)&lds[c * 512 + lane * 8] = w;
      }
      if (kt < kiters - 1) {
#pragma unroll
        for (int i = 0; i < 2; ++i) {
          const float* s = Af + (long)arow[i] * K + (kt + 1) * 32 + (acs[i] >> 1);
          pa[i][0] = *(const f32x4*)s;
          pa[i][1] = *(const f32x4*)(s + 4);
        }
      }
    }
    __syncthreads();

    bf16x8 af[4], bf[4];
#pragma unroll
    for (int m = 0; m < 4; ++m)
      af[m] = *(const bf16x8*)((const char*)lds + (wr * 64 + m * 16 + r15) * 64 + (g * 16 ^ asw));
#pragma unroll
    for (int n = 0; n < 4; ++n)
      bf[n] = *(const bf16x8*)((const char*)lds + 8192 +
                               (wc * 64 + n * 16 + r15) * 64 + (g * 16 ^ asw));
#pragma unroll
    for (int m = 0; m < 4; ++m)
#pragma unroll
      for (int n = 0; n < 4; ++n)
        acc[m][n] = __builtin_amdgcn_mfma_f32_16x16x32_bf16(af[m], bf[n], acc[m][n], 0, 0, 0);
    __syncthreads();
  }

  const long crow0 = (long)by * 128 + wr * 64;
  const long ccol0 = (long)bx * 128 + wc * 64;
#pragma unroll
  for (int n = 0; n < 4; ++n) {
    const long col = ccol0 + n * 16 + r15;
    const float bv = BIAS ? bias[col] : 0.f;
#pragma unroll
    for (int m = 0; m < 4; ++m) {
      const f32x4 v = acc[m][n];
#pragma unroll
      for (int j = 0; j < 4; ++j) {
        const long row = crow0 + m * 16 + g * 4 + j;
        const float val = (v[j] + bv) * scale;
        const long idx = TRANSOUT ? (col * (long)ldc + row) : (row * (long)ldc + col);
        (Cout + (long)bz * strideC)[idx] = f_to_bf_bits(val);
      }
    }
  }
}

// ---------------- merged V + KM projection (one dispatch, A = audio fp32) ----------------
// grid 8(nx) x 8(ny) x 16(bz): bx<4 -> V half (B = WvT rows, +bias bv, Vt[d][s] transposed out);
// bx>=4 -> KM half (B = G rows, KM[s][d] out).  Same m97 AFP32 structure as gemm_kernel.
__global__ __launch_bounds__(256) void projdual_kernel(
    const float* __restrict__ audio,        // [16][1024][512] fp32
    const unsigned short* __restrict__ wvt, // [512][512] bf16 (Wv^T)
    const unsigned short* __restrict__ G,   // [512][512] bf16
    const float* __restrict__ bv,
    unsigned short* __restrict__ Vt,        // [16][512][1024]
    unsigned short* __restrict__ KMb) {     // [16][1024][512]
  __shared__ unsigned short lds[8192];
  const int nwg = gridDim.x;                // 1024
  const int chunk = nwg >> 3;
  const int bid = blockIdx.x;
  const int swz = (bid & 7) * chunk + (bid >> 3);
  const int bx = swz & 7;
  const int t1 = swz >> 3;
  const int by = t1 & 7;
  const int bz = t1 >> 3;

  const int tid = threadIdx.x;
  const int lane = tid & 63;
  const int wv = tid >> 6;
  const int wr = wv >> 1, wc = wv & 1;
  const float* Af = audio + (long)bz * 1024 * 512 + (long)by * 128 * 512;
  const unsigned short* Bb = (bx < 4) ? (wvt + (long)bx * 128 * 512)
                                      : (G + (long)(bx - 4) * 128 * 512);

  f32x4 acc[4][4];
#pragma unroll
  for (int m = 0; m < 4; ++m)
#pragma unroll
    for (int n = 0; n < 4; ++n) acc[m][n] = (f32x4){0.f, 0.f, 0.f, 0.f};

  const int r15 = lane & 15, g = lane >> 4;
  const int asw = fsw(r15);

  int arow[2], acs[2];
#pragma unroll
  for (int i = 0; i < 2; ++i) {
    const int c = i * 4 + wv;
    const int boff = c * 1024 + lane * 16;
    arow[i] = boff >> 6;
    acs[i] = (boff & 63) ^ fsw(arow[i]);
  }
  f32x4 pa[2][2];
#pragma unroll
  for (int i = 0; i < 2; ++i) {
    const float* sp = Af + (long)arow[i] * 512 + (acs[i] >> 1);
    pa[i][0] = *(const f32x4*)sp;
    pa[i][1] = *(const f32x4*)(sp + 4);
  }

  for (int kt = 0; kt < 16; ++kt) {
#pragma unroll
    for (int i = 0; i < 2; ++i) {
      const int c = i * 4 + wv;
      const char* srcB = (const char*)Bb + (long)arow[i] * 1024 + kt * 64 + acs[i];
      __builtin_amdgcn_global_load_lds(
          (const AS1 void*)srcB, (AS3 void*)(lds + 4096 + c * 512), 16, 0, 0);
    }
#pragma unroll
    for (int i = 0; i < 2; ++i) {
      const int c = i * 4 + wv;
      bf16x8 wq;
#pragma unroll
      for (int e = 0; e < 4; ++e) {
        wq[e] = (short)f_to_bf_bits(pa[i][0][e]);
        wq[4 + e] = (short)f_to_bf_bits(pa[i][1][e]);
      }
      *(bf16x8*)&lds[c * 512 + lane * 8] = wq;
    }
    if (kt < 15) {
#pragma unroll
      for (int i = 0; i < 2; ++i) {
        const float* sp = Af + (long)arow[i] * 512 + (kt + 1) * 32 + (acs[i] >> 1);
        pa[i][0] = *(const f32x4*)sp;
        pa[i][1] = *(const f32x4*)(sp + 4);
      }
    }
    __syncthreads();

    bf16x8 af[4], bf[4];
#pragma unroll
    for (int m = 0; m < 4; ++m)
      af[m] = *(const bf16x8*)((const char*)lds + (wr * 64 + m * 16 + r15) * 64 + (g * 16 ^ asw));
#pragma unroll
    for (int n = 0; n < 4; ++n)
      bf[n] = *(const bf16x8*)((const char*)lds + 8192 +
                               (wc * 64 + n * 16 + r15) * 64 + (g * 16 ^ asw));
#pragma unroll
    for (int m = 0; m < 4; ++m)
#pragma unroll
      for (int n = 0; n < 4; ++n)
        acc[m][n] = __builtin_amdgcn_mfma_f32_16x16x32_bf16(af[m], bf[n], acc[m][n], 0, 0, 0);
    __syncthreads();
  }

  const long crow0 = (long)by * 128 + wr * 64;     // s-index
  const long ccol0 = (long)bx * 128 + wc * 64;     // combined col (0..1023)
#pragma unroll
  for (int n = 0; n < 4; ++n) {
    const long col = ccol0 + n * 16 + r15;
    const float bvv = (bx < 4) ? bv[col] : 0.f;
#pragma unroll
    for (int m = 0; m < 4; ++m) {
      const f32x4 v = acc[m][n];
#pragma unroll
      for (int j = 0; j < 4; ++j) {
        const long row = crow0 + m * 16 + g * 4 + j;
        const float val = v[j] + bvv;
        if (bx < 4)
          Vt[(long)bz * 512 * 1024 + col * 1024 + row] = f_to_bf_bits(val);
        else
          KMb[(long)bz * 1024 * 512 + row * 512 + (col - 512)] = f_to_bf_bits(val);
      }
    }
  }
}

// ---------------- 256x256 GEMM, K-slice ring-4 + counted vmcnt (r11-verified core) --------
// AFP32: A reg-staged from fp32 (global_load x4 -> cvt -> ds_write), lead-2 reg sets,
//        write of slice s+2 at phase s; lgkmcnt(0) BEFORE the barrier so ds_writes of s+2
//        retire before C(s).  WAR: A-slot (s+2)&3 = s-2, whose readers retired reads at
//        their lgkm < C(s-1) < C(s).  vmcnt: 6 ops/phase; steady vmcnt(6), tail 2 -> 0.
// !AFP32 (PV): r11 staging (4 gload_lds/slice), steady vmcnt(4) -> 0.
// EXPSTATS: C = exp(acc + cbias[col]) bf16; per-row 256-col partial sums -> stats[row*4+bx].
// DIVSTATS: prologue 1/sum(stats[row][0..3]); C = acc * invl fp32.
template <bool EXPSTATS, bool DIVSTATS, bool AFP32>
__global__ __launch_bounds__(512, 2) void gemm256_kernel(
    const void* __restrict__ Aptr,          // [M][K] bf16 or fp32, per batch
    const unsigned short* __restrict__ BT,  // [N][K] bf16, per batch
    void* __restrict__ Cout,
    const int K,
    const long strideA, const long strideBT, const long strideC, const int ldc,
    const int nx, const int ny, float* __restrict__ stats,
    const float* __restrict__ cbias) {
  __shared__ __align__(16) char halfb[4][32768];  // per slice: A[256][64B] | B[256][64B]
  __shared__ float ssum[256][4];
  __shared__ float invl[256];

  const int nwg = gridDim.x;
  const int chunk = nwg >> 3;
  const int bid = blockIdx.x;
  const int swz = (bid & 7) * chunk + (bid >> 3);
  const int bx = swz % nx;
  const int t1 = swz / nx;
  const int by = t1 % ny;
  const int bz = t1 / ny;

  const int tid = threadIdx.x;
  const int lane = tid & 63;
  const int w = tid >> 6;            // 0..7
  const int wm = w >> 2, wn = w & 3; // 2 x 4 wave grid
  const int r15 = lane & 15, g = lane >> 4;
  const int asw = fsw(r15);          // read-side chunk swizzle

  const unsigned short* Abf = (const unsigned short*)Aptr + (long)bz * strideA + (long)by * 256 * K;
  const float* Afp = (const float*)Aptr + (long)bz * strideA + (long)by * 256 * K;
  const char* Abyt = (const char*)Abf;
  const char* Bbyt = (const char*)(BT + (long)bz * strideBT + (long)bx * 256 * K);
  const long rsb = (long)K * 2;      // bytes per bf16 source row

  if (DIVSTATS) {
    if (tid < 256) {
      const f32x4 s = *(const f32x4*)&stats[((long)bz * 4096 + (long)by * 256 + tid) * 4];
      invl[tid] = 1.f / (s[0] + s[1] + s[2] + s[3]);
    }
  }
  __builtin_amdgcn_sched_barrier(0);

  // staging geometry: thread tid -> physical chunk (tid&3) of row (tid>>2); dest = tid*16.
  const int srow0 = tid >> 2;                           // 0..127
  const int scol = ((tid & 3) << 4) ^ fsw(srow0);       // inverse-swizzled source col (bytes, bf16)
  const long aoff0 = (long)srow0 * rsb + scol;          // rows 0-127
  const long aoff1 = (long)(srow0 + 128) * rsb + scol;  // rows 128-255 (fsw uses bits 1-2 only)
  const int dbase = tid * 16;
  // fp32 A sources (AFP32): elem offset = scol/2
  const float* AF0 = Afp + (long)srow0 * K + (scol >> 1);
  const float* AF1 = Afp + (long)(srow0 + 128) * K + (scol >> 1);

  auto gl = [&](const char* src, char* dst) {
    __builtin_amdgcn_global_load_lds((const AS1 void*)src, (AS3 void*)dst, 16, 0, 0);
  };
  auto stage = [&](int s) {          // !AFP32 full staging (A+B)
    char* h = halfb[s & 3];
    const long kb = (long)s * 64;
    gl(Abyt + aoff0 + kb, h + dbase);
    gl(Abyt + aoff1 + kb, h + 8192 + dbase);
    gl(Bbyt + aoff0 + kb, h + 16384 + dbase);
    gl(Bbyt + aoff1 + kb, h + 24576 + dbase);
  };
  auto stageB = [&](int s) {         // AFP32: B only
    char* h = halfb[s & 3];
    const long kb = (long)s * 64;
    gl(Bbyt + aoff0 + kb, h + 16384 + dbase);
    gl(Bbyt + aoff1 + kb, h + 24576 + dbase);
  };

  f32x4 acc[8][4];
#pragma unroll
  for (int m = 0; m < 8; ++m)
#pragma unroll
    for (int n = 0; n < 4; ++n) acc[m][n] = (f32x4){0.f, 0.f, 0.f, 0.f};

  const int kslices = K >> 5;
  f32x4 paE[4], paO[4];              // two in-flight fp32 A reg sets (parity of slice)

  if (AFP32) {
    // prologue: A(0),A(1) via regs->LDS; B(0..2) in flight; regs hold A(2),A(3); full drain.
    paE[0] = *(const f32x4*)AF0;       paE[1] = *(const f32x4*)(AF0 + 4);
    paE[2] = *(const f32x4*)AF1;       paE[3] = *(const f32x4*)(AF1 + 4);
    paO[0] = *(const f32x4*)(AF0 + 32); paO[1] = *(const f32x4*)(AF0 + 36);
    paO[2] = *(const f32x4*)(AF1 + 32); paO[3] = *(const f32x4*)(AF1 + 36);
    asm volatile("s_waitcnt vmcnt(0)" ::: "memory");
#pragma unroll
    for (int hv = 0; hv < 2; ++hv) {
      const f32x4* P = hv ? paO : paE;
      char* h = halfb[hv];
      bf16x8 w0, w1;
#pragma unroll
      for (int e = 0; e < 4; ++e) {
        w0[e] = (short)f_to_bf_bits(P[0][e]); w0[4 + e] = (short)f_to_bf_bits(P[1][e]);
        w1[e] = (short)f_to_bf_bits(P[2][e]); w1[4 + e] = (short)f_to_bf_bits(P[3][e]);
      }
      *(bf16x8*)(h + dbase) = w0;
      *(bf16x8*)(h + 8192 + dbase) = w1;
    }
    stageB(0); stageB(1); stageB(2);
    paE[0] = *(const f32x4*)(AF0 + 64); paE[1] = *(const f32x4*)(AF0 + 68);   // A(2)
    paE[2] = *(const f32x4*)(AF1 + 64); paE[3] = *(const f32x4*)(AF1 + 68);
    paO[0] = *(const f32x4*)(AF0 + 96); paO[1] = *(const f32x4*)(AF0 + 100);  // A(3)
    paO[2] = *(const f32x4*)(AF1 + 96); paO[3] = *(const f32x4*)(AF1 + 100);
    __syncthreads();  // full drain once at warmup: slices 0-2 resident, regs valid
  } else {
    stage(0); stage(1); stage(2);
    asm volatile("s_waitcnt vmcnt(8)" ::: "memory");
    __builtin_amdgcn_s_barrier();
    __builtin_amdgcn_sched_barrier(0);
  }

#define PHASE(S, PA)                                                                   \
  {                                                                                    \
    const int s_ = (S);                                                                \
    const char* hA = halfb[s_ & 3];                                                    \
    const char* hB = halfb[s_ & 3] + 16384;                                            \
    bf16x8 fa[8], fb[4];                                                               \
    _Pragma("unroll") for (int m = 0; m < 8; ++m)                                      \
      fa[m] = *(const bf16x8*)(hA + (wm * 128 + m * 16 + r15) * 64 + ((g * 16) ^ asw)); \
    _Pragma("unroll") for (int n = 0; n < 4; ++n)                                      \
      fb[n] = *(const bf16x8*)(hB + (wn * 64 + n * 16 + r15) * 64 + ((g * 16) ^ asw)); \
    __builtin_amdgcn_sched_barrier(0);                                                 \
    if (AFP32) {                                                                       \
      if (s_ < kslices - 3)       asm volatile("s_waitcnt vmcnt(6)" ::: "memory");     \
      else if (s_ == kslices - 3) asm volatile("s_waitcnt vmcnt(2)" ::: "memory");     \
      else                        asm volatile("s_waitcnt vmcnt(0)" ::: "memory");     \
    } else {                                                                           \
      if (s_ < kslices - 2) asm volatile("s_waitcnt vmcnt(4)" ::: "memory");           \
      else                  asm volatile("s_waitcnt vmcnt(0)" ::: "memory");           \
    }                                                                                  \
    asm volatile("s_waitcnt lgkmcnt(0)" ::: "memory");                                 \
    __builtin_amdgcn_s_barrier();                                                      \
    __builtin_amdgcn_sched_barrier(0);                                                 \
    if (AFP32) {                                                                       \
      if (s_ + 2 < kslices) {                                                          \
        char* hW = halfb[(s_ + 2) & 3];                                                \
        bf16x8 w0, w1;                                                                 \
        _Pragma("unroll") for (int e = 0; e < 4; ++e) {                                \
          w0[e] = (short)f_to_bf_bits(PA[0][e]);                                       \
          w0[4 + e] = (short)f_to_bf_bits(PA[1][e]);                                   \
          w1[e] = (short)f_to_bf_bits(PA[2][e]);                                       \
          w1[4 + e] = (short)f_to_bf_bits(PA[3][e]);                                   \
        }                                                                              \
        *(bf16x8*)(hW + dbase) = w0;                                                   \
        *(bf16x8*)(hW + 8192 + dbase) = w1;                                            \
      }                                                                                \
      if (s_ + 3 < kslices) stageB(s_ + 3);                                            \
      if (s_ + 4 < kslices) {                                                          \
        const float* p0 = AF0 + (long)(s_ + 4) * 32;                                   \
        const float* p1 = AF1 + (long)(s_ + 4) * 32;                                   \
        PA[0] = *(const f32x4*)p0; PA[1] = *(const f32x4*)(p0 + 4);                    \
        PA[2] = *(const f32x4*)p1; PA[3] = *(const f32x4*)(p1 + 4);                    \
      }                                                                                \
    } else {                                                                           \
      if (s_ + 3 < kslices) stage(s_ + 3);                                             \
    }                                                                                  \
    __builtin_amdgcn_s_setprio(1);                                                     \
    _Pragma("unroll") for (int m = 0; m < 8; ++m)                                      \
      _Pragma("unroll") for (int n = 0; n < 4; ++n)                                    \
        acc[m][n] = __builtin_amdgcn_mfma_f32_16x16x32_bf16(fa[m], fb[n], acc[m][n], 0, 0, 0); \
    __builtin_amdgcn_s_setprio(0);                                                     \
    __builtin_amdgcn_sched_barrier(0);                                                 \
  }

  for (int s = 0; s < kslices; s += 2) {
    PHASE(s, paE);
    PHASE(s + 1, paO);
  }
#undef PHASE

  if (EXPSTATS) {
    float cb[4];
#pragma unroll
    for (int n = 0; n < 4; ++n)
      cb[n] = cbias[(long)bz * 1024 + (long)bx * 256 + wn * 64 + n * 16 + r15];
#pragma unroll
    for (int m = 0; m < 8; ++m)
#pragma unroll
      for (int n = 0; n < 4; ++n)
#pragma unroll
        for (int j = 0; j < 4; ++j) acc[m][n][j] = __expf(acc[m][n][j] + cb[n]);
#pragma unroll
    for (int m = 0; m < 8; ++m)
#pragma unroll
      for (int j = 0; j < 4; ++j) {
        float s = acc[m][0][j] + acc[m][1][j] + acc[m][2][j] + acc[m][3][j];
        s += __shfl_xor(s, 1);
        s += __shfl_xor(s, 2);
        s += __shfl_xor(s, 4);
        s += __shfl_xor(s, 8);
        if (r15 == 0) ssum[wm * 128 + m * 16 + g * 4 + j][wn] = s;
      }
    __syncthreads();
    if (tid < 256) {
      const float t = ssum[tid][0] + ssum[tid][1] + ssum[tid][2] + ssum[tid][3];
      stats[((long)bz * 4096 + (long)by * 256 + tid) * 4 + bx] = t;
    }
  }

  // epilogue: C/D layout col = lane&15, row = (lane>>4)*4 + j
  const long crow0 = (long)by * 256 + wm * 128;
  const long ccol0 = (long)bx * 256 + wn * 64;
#pragma unroll
  for (int m = 0; m < 8; ++m)
#pragma unroll
    for (int j = 0; j < 4; ++j) {
      const int rl = wm * 128 + m * 16 + g * 4 + j;
      const long row = crow0 + m * 16 + g * 4 + j;
#pragma unroll
      for (int n = 0; n < 4; ++n) {
        const long col = ccol0 + n * 16 + r15;
        if (EXPSTATS) {
          ((unsigned short*)Cout + (long)bz * strideC)[row * (long)ldc + col] =
              f_to_bf_bits(acc[m][n][j]);
        } else {
          const float sc = DIVSTATS ? invl[rl] : 1.f;
          ((float*)Cout + (long)bz * strideC)[row * (long)ldc + col] = acc[m][n][j] * sc;
        }
      }
    }
}

extern "C" void kernel_launch(void* const* d_in, const int* in_sizes, int n_in,
                              void* d_out, int out_size, void* d_ws, size_t ws_size,
                              hipStream_t stream) {
  (void)in_sizes; (void)n_in; (void)out_size; (void)ws_size;
  const float* x     = (const float*)d_in[0];  // [16][4096][512]
  const float* audio = (const float*)d_in[1];  // [16][1024][512]
  const float* Wq    = (const float*)d_in[2];  // [512][512]  (in x out)
  const float* bq    = (const float*)d_in[3];
  const float* Wk    = (const float*)d_in[4];
  const float* bk    = (const float*)d_in[5];  (void)bk;  // cancels in softmax
  const float* Wv    = (const float*)d_in[6];
  const float* bv    = (const float*)d_in[7];
  float* out = (float*)d_out;                  // [16][4096][512] fp32

  const float s = 0.044194173824159216f;       // 1/sqrt(512)

  char* ws = (char*)d_ws;
  size_t off = 0;
  auto carve = [&](size_t bytes) { char* p = ws + off; off += (bytes + 255) & ~(size_t)255; return p; };
  unsigned short* wkb = (unsigned short*)carve((size_t)512 * 512 * 2);    // Wk bf16 verbatim
  unsigned short* wvt = (unsigned short*)carve((size_t)512 * 512 * 2);    // Wv^T bf16
  unsigned short* G   = (unsigned short*)carve((size_t)512 * 512 * 2);    // G = Wq Wk^T / sqrt(d)
  unsigned short* KMb = (unsigned short*)carve((size_t)16384 * 512 * 2);  // KM = audio G^T
  unsigned short* Vt  = (unsigned short*)carve((size_t)16384 * 512 * 2);  // V^T bf16 [B][512][1024]
  unsigned short* Pb  = (unsigned short*)carve((size_t)65536 * 1024 * 2); // P = exp(S) bf16
  float*          ls  = (float*)carve((size_t)65536 * 4 * 4);             // row sums [B*HW][4]
  float*          wv_ = (float*)carve((size_t)512 * 4);                   // w = s * Wk bq
  float*          cv  = (float*)carve((size_t)16384 * 4);                 // c_j per (b,j)

  // 1) merged prep (Wk cvt + Wv transpose + wvec), then G and cvec
  prep_kernel<<<640, 256, 0, stream>>>(Wk, Wv, bq, wkb, wvt, wv_, s);
  gemm_kernel<false, false, true><<<16, 256, 0, stream>>>(
      Wq, wkb, nullptr, G, 512, s, 0, 0, 0, 512, 4, 4);
  cvec_kernel<<<4096, 256, 0, stream>>>(audio, wv_, cv);
  // 2) merged V + KM projections (A = audio fp32, one full-GPU dispatch)
  projdual_kernel<<<8 * 8 * 16, 256, 0, stream>>>(audio, wvt, G, bv, Vt, KMb);
  // 3) P = exp(x KM^T + c_j) bf16 + per-row partial sums (A = x fp32, fused convert)
  gemm256_kernel<true, false, true><<<4 * 16 * 16, 512, 0, stream>>>(
      x, KMb, Pb, 512,
      (long)4096 * 512, (long)1024 * 512, (long)4096 * 1024, 1024, 4, 16, ls, cv);
  // 4) out = (P V) / l
  gemm256_kernel<false, true, false><<<2 * 16 * 16, 512, 0, stream>>>(
      Pb, Vt, out, 1024,
      (long)4096 * 1024, (long)512 * 1024, (long)4096 * 512, 512, 2, 16, ls, nullptr);
}